// Round 7
// baseline (224.811 us; speedup 1.0000x reference)
//
#include <hip/hip_runtime.h>
#include <hip/hip_bf16.h>
#include <math.h>

#define B_ 8
#define N_ 4096
#define C_ 256
#define H_ 8
#define HD_ 32
#define BN_ (B_ * N_)  // 32768
#define E_ ((size_t)BN_ * C_)  // 8388608

typedef __attribute__((ext_vector_type(8))) short short8;
typedef __attribute__((ext_vector_type(4))) float f32x4;

__device__ __forceinline__ float b2f(__hip_bfloat16 x) { return __bfloat162float(x); }

__device__ __forceinline__ void gl_lds16(const void* gp, void* lp) {
    __builtin_amdgcn_global_load_lds(
        (const __attribute__((address_space(1))) unsigned int*)gp,
        (__attribute__((address_space(3))) unsigned int*)lp,
        16, 0, 0);
}

__device__ __forceinline__ float fast_abspow(float v, float p) {
    float av = fabsf(v);
    return (av > 0.f) ? exp2f(p * __log2f(av)) : 0.f;
}

__device__ __forceinline__ float bf_lo(unsigned u) { return __uint_as_float(u << 16); }
__device__ __forceinline__ float bf_hi(unsigned u) { return __uint_as_float(u & 0xffff0000u); }
__device__ __forceinline__ unsigned short f2bfbits(float f) {
    __hip_bfloat16 h = __float2bfloat16(f);
    return *(unsigned short*)&h;
}

// ---- merged converts: blocks [0,8192): x -> bf16 ; [8192, 8272]: weights+powers ----
__global__ __launch_bounds__(256) void cvt_all(
    const float* __restrict__ x, const float* __restrict__ Wqg,
    const float* __restrict__ Wkv, const float* __restrict__ Wp,
    const float* __restrict__ pp,
    __hip_bfloat16* __restrict__ xb, __hip_bfloat16* __restrict__ Wt1,
    __hip_bfloat16* __restrict__ Wt2, float* __restrict__ powers)
{
    int t = threadIdx.x;
    int bid0 = blockIdx.x;
    if (bid0 < 8192) {
        size_t i = ((size_t)bid0 * 256 + t) * 4;
        float4 v = *(const float4*)&x[i];
        xb[i + 0] = __float2bfloat16(v.x);
        xb[i + 1] = __float2bfloat16(v.y);
        xb[i + 2] = __float2bfloat16(v.z);
        xb[i + 3] = __float2bfloat16(v.w);
        return;
    }
    int bid = bid0 - 8192;
    if (bid == 80) {
        powers[t] = 1.0f + 4.0f / (1.0f + expf(-pp[t]));
        return;
    }
    __shared__ float tile[64][65];
    const float* src;
    __hip_bfloat16* dst;
    int scols, tr, tc, dn0;
    if (bid < 32)      { src = Wqg; scols = 512; tr = bid >> 3;        tc = bid & 7;        dst = Wt1; dn0 = tc * 64; }
    else if (bid < 64) { src = Wkv; scols = 512; tr = (bid - 32) >> 3; tc = (bid - 32) & 7; dst = Wt1; dn0 = 512 + tc * 64; }
    else               { src = Wp;  scols = 256; tr = (bid - 64) >> 2; tc = (bid - 64) & 3; dst = Wt2; dn0 = tc * 64; }
    int tx = t & 63, ty = t >> 6;
    #pragma unroll
    for (int i = 0; i < 16; i++) {
        int r = ty + i * 4;
        tile[r][tx] = src[(size_t)(tr * 64 + r) * scols + tc * 64 + tx];
    }
    __syncthreads();
    #pragma unroll
    for (int i = 0; i < 16; i++) {
        int n_local = ty + i * 4;
        dst[(size_t)(dn0 + n_local) * 256 + tr * 64 + tx] = __float2bfloat16(tile[tx][n_local]);
    }
}

// ---- GEMM1: 128x128 tile, BK=64; epilogue via LDS transpose + uint4 stores ----
#define EP 132  // epilogue LDS row stride (shorts)
__global__ __launch_bounds__(256) void gemm1_mfma(
    const __hip_bfloat16* __restrict__ xb, const __hip_bfloat16* __restrict__ Wt1,
    const float* __restrict__ powers,
    __hip_bfloat16* __restrict__ q16, __hip_bfloat16* __restrict__ k16,
    __hip_bfloat16* __restrict__ g16, __hip_bfloat16* __restrict__ v16)
{
    __shared__ __align__(16) unsigned short SMEM[128 * EP];  // >= 16384 staging shorts
    unsigned short* As = SMEM;          // 8192 shorts
    unsigned short* Bs = SMEM + 8192;   // 8192 shorts
    int t = threadIdx.x;
    int w = t >> 6, l = t & 63;
    int row0 = blockIdx.x * 128;
    int col0 = blockIdx.y * 128;
    int wm = (w >> 1) * 64, wn = (w & 1) * 64;
    int lane15 = l & 15, quad = l >> 4;
    int srow = l >> 2;
    int skcol = (l & 3) * 8;

    f32x4 acc[4][4];
    #pragma unroll
    for (int mi = 0; mi < 4; mi++)
        #pragma unroll
        for (int ni = 0; ni < 4; ni++) acc[mi][ni] = (f32x4){0.f, 0.f, 0.f, 0.f};

    for (int k0 = 0; k0 < 256; k0 += 64) {
        #pragma unroll
        for (int kh = 0; kh < 2; kh++) {
            #pragma unroll
            for (int i = 0; i < 2; i++) {
                int r = i * 64 + w * 16 + srow;
                int kc = k0 + kh * 32 + skcol;
                gl_lds16(&xb[(size_t)(row0 + r) * 256 + kc],
                         &As[kh * 4096 + (i * 64 + w * 16) * 32]);
                gl_lds16(&Wt1[(size_t)(col0 + r) * 256 + kc],
                         &Bs[kh * 4096 + (i * 64 + w * 16) * 32]);
            }
        }
        __syncthreads();
        #pragma unroll
        for (int kh = 0; kh < 2; kh++) {
            short8 a[4], b[4];
            #pragma unroll
            for (int mi = 0; mi < 4; mi++)
                a[mi] = *(const short8*)&As[kh * 4096 + (wm + mi * 16 + lane15) * 32 + quad * 8];
            #pragma unroll
            for (int ni = 0; ni < 4; ni++)
                b[ni] = *(const short8*)&Bs[kh * 4096 + (wn + ni * 16 + lane15) * 32 + quad * 8];
            #pragma unroll
            for (int mi = 0; mi < 4; mi++)
                #pragma unroll
                for (int ni = 0; ni < 4; ni++)
                    acc[mi][ni] = __builtin_amdgcn_mfma_f32_16x16x32_bf16(a[mi], b[ni], acc[mi][ni], 0, 0, 0);
        }
        __syncthreads();
    }

    // epilogue phase 1: transformed bf16 tile -> LDS (staging is dead now)
    int region = blockIdx.y >> 1;  // 0:q 1:g 2:k 3:v
    bool dopow = (region == 0) || (region == 2);
    #pragma unroll
    for (int mi = 0; mi < 4; mi++) {
        #pragma unroll
        for (int ni = 0; ni < 4; ni++) {
            int lrow = wm + mi * 16 + quad * 4;
            int lcol = wn + ni * 16 + lane15;
            float p = powers[(col0 + lcol) & 255];
            #pragma unroll
            for (int r = 0; r < 4; r++) {
                float v = acc[mi][ni][r];
                float o = dopow ? fast_abspow(v, p) : v;
                SMEM[(lrow + r) * EP + lcol] = f2bfbits(o);
            }
        }
    }
    __syncthreads();
    // epilogue phase 2: coalesced uint4 stores
    __hip_bfloat16* dst = (region == 0) ? q16 : (region == 1) ? g16 : (region == 2) ? k16 : v16;
    int sr = t >> 1, sc = (t & 1) * 64;
    const unsigned short* src = &SMEM[sr * EP + sc];
    __hip_bfloat16* gp = dst + (size_t)(row0 + sr) * 256 + ((col0 + sc) & 255);
    #pragma unroll
    for (int j = 0; j < 8; j++)
        *(uint4*)(gp + j * 8) = *(const uint4*)(src + j * 8);
}

// ---- merged: blocks [0,256): kvmat (atomic accumulate); [256, 2304): conv ----
__global__ __launch_bounds__(256) void kvmat_conv(
    const __hip_bfloat16* __restrict__ k16, const __hip_bfloat16* __restrict__ v16,
    float* __restrict__ kv_mat2,
    const float* __restrict__ w, const float* __restrict__ bias,
    __hip_bfloat16* __restrict__ vloc)
{
    __shared__ __align__(16) float SM[4640];
    int t = threadIdx.x;
    int bid = blockIdx.x;
    if (bid < 256) {
        unsigned short* Kl = (unsigned short*)SM;         // 4096 shorts
        unsigned short* Vl = (unsigned short*)SM + 4096;  // 4096 shorts
        int b = bid >> 5, seg = bid & 31;
        int h = t >> 5;
        float acc[32];
        #pragma unroll
        for (int e = 0; e < 32; e++) acc[e] = 0.f;
        const size_t base = (size_t)b * N_ * 256;
        int row = t >> 4, colb = (t & 15) * 16;
        for (int n0 = seg * 128; n0 < seg * 128 + 128; n0 += 16) {
            const uint4* ks = (const uint4*)(k16 + base + (size_t)(n0 + row) * 256 + colb);
            uint4 ka = ks[0], kb = ks[1];
            const uint4* vs = (const uint4*)(v16 + base + (size_t)(n0 + row) * 256 + colb);
            uint4 va = vs[0], vb = vs[1];
            __syncthreads();
            uint4* kd4 = (uint4*)&Kl[row * 256 + colb];
            kd4[0] = ka; kd4[1] = kb;
            uint4* vd4 = (uint4*)&Vl[row * 256 + colb];
            vd4[0] = va; vd4[1] = vb;
            __syncthreads();
            #pragma unroll
            for (int nn = 0; nn < 16; nn++) {
                float kd = bf_lo((unsigned)Kl[nn * 256 + t]);
                const uint4* vp = (const uint4*)&Vl[nn * 256 + h * 32];
                uint4 v0 = vp[0], v1 = vp[1], v2 = vp[2], v3 = vp[3];
                unsigned us[16] = {v0.x, v0.y, v0.z, v0.w, v1.x, v1.y, v1.z, v1.w,
                                   v2.x, v2.y, v2.z, v2.w, v3.x, v3.y, v3.z, v3.w};
                #pragma unroll
                for (int j = 0; j < 16; j++) {
                    acc[2 * j]     += kd * bf_lo(us[j]);
                    acc[2 * j + 1] += kd * bf_hi(us[j]);
                }
            }
        }
        float* dst = kv_mat2 + (size_t)b * 8192;
        #pragma unroll
        for (int e = 0; e < 32; e++) atomicAdd(&dst[e * 256 + t], acc[e]);
    } else {
        float* img = SM;          // 64*72 floats
        float* wl  = SM + 4608;   // 25 floats
        int gid = bid - 256;
        int DD = gid & 31;
        if (t < 128) {
            int row = t >> 1, side = (t & 1) * 68;
            *(float4*)&img[row * 72 + side] = (float4){0.f, 0.f, 0.f, 0.f};
        }
        if (t < 25) wl[t] = w[DD * 25 + t];
        {
            int row = t >> 2, colb = (t & 3) * 16;
            const uint4* src = (const uint4*)(v16 + (size_t)gid * 4096 + row * 64 + colb);
            uint4 u0 = src[0], u1 = src[1];
            float4* d = (float4*)&img[row * 72 + 4 + colb];
            d[0] = (float4){bf_lo(u0.x), bf_hi(u0.x), bf_lo(u0.y), bf_hi(u0.y)};
            d[1] = (float4){bf_lo(u0.z), bf_hi(u0.z), bf_lo(u0.w), bf_hi(u0.w)};
            d[2] = (float4){bf_lo(u1.x), bf_hi(u1.x), bf_lo(u1.y), bf_hi(u1.y)};
            d[3] = (float4){bf_lo(u1.z), bf_hi(u1.z), bf_lo(u1.w), bf_hi(u1.w)};
        }
        __syncthreads();
        float bs = bias[DD];
        int x0 = (t & 15) * 4, yb = t >> 4;
        #pragma unroll
        for (int s = 0; s < 4; s++) {
            int y = yb + s * 16;
            float a0 = bs, a1 = bs, a2 = bs, a3 = bs;
            #pragma unroll
            for (int ky = 0; ky < 5; ky++) {
                int row = y + ky - 2;
                if (row < 0 || row >= 64) continue;
                const float* rp = &img[row * 72 + x0];
                float4 w0 = *(const float4*)rp;
                float4 w1 = *(const float4*)(rp + 4);
                float4 w2 = *(const float4*)(rp + 8);
                float win[12] = {w0.x, w0.y, w0.z, w0.w, w1.x, w1.y, w1.z, w1.w,
                                 w2.x, w2.y, w2.z, w2.w};
                #pragma unroll
                for (int kx = 0; kx < 5; kx++) {
                    float wt = wl[ky * 5 + kx];
                    a0 += wt * win[2 + kx];
                    a1 += wt * win[3 + kx];
                    a2 += wt * win[4 + kx];
                    a3 += wt * win[5 + kx];
                }
            }
            unsigned lo = (unsigned)f2bfbits(a0) | ((unsigned)f2bfbits(a1) << 16);
            unsigned hi = (unsigned)f2bfbits(a2) | ((unsigned)f2bfbits(a3) << 16);
            *(uint2*)(vloc + (size_t)gid * 4096 + y * 64 + x0) = (uint2){lo, hi};
        }
    }
}

// ---- fused MFMA att + gate + GEMM2: grid 512, 64 rows per block ----
#define A2P 264
__global__ __launch_bounds__(256) void att_gemm2(
    const __hip_bfloat16* __restrict__ q16, const float* __restrict__ kv_mat2,
    const __hip_bfloat16* __restrict__ vloc, const __hip_bfloat16* __restrict__ g16,
    const __hip_bfloat16* __restrict__ Wt2, const float* __restrict__ bp,
    float* __restrict__ out)
{
    __shared__ __align__(16) unsigned short QA[64 * A2P];
    __shared__ __align__(16) unsigned short Bs[256 * 32];
    int t = threadIdx.x;
    int w = t >> 6, l = t & 63;
    int r0 = blockIdx.x * 64;
    int b = r0 >> 12, n0 = r0 & 4095;
    int lane15 = l & 15, quad = l >> 4;
    int h0 = w * 2;

    {
        const uint4* qsrc = (const uint4*)(q16 + (size_t)(r0 + (t >> 2)) * 256 + (t & 3) * 64);
        uint4* qdst = (uint4*)&QA[(t >> 2) * A2P + (t & 3) * 64];
        #pragma unroll
        for (int j = 0; j < 8; j++) qdst[j] = qsrc[j];
    }
    __syncthreads();

    short8 afr[4][2];
    #pragma unroll
    for (int m = 0; m < 4; m++)
        #pragma unroll
        for (int hh = 0; hh < 2; hh++)
            afr[m][hh] = *(const short8*)&QA[(m * 16 + lane15) * A2P + (h0 + hh) * 32 + quad * 8];

    short8 bfr[2][2];
    #pragma unroll
    for (int hh = 0; hh < 2; hh++) {
        #pragma unroll
        for (int nt = 0; nt < 2; nt++) {
            const float4* kp = (const float4*)(kv_mat2 + (size_t)b * 8192 +
                (size_t)(nt * 16 + lane15) * 256 + (h0 + hh) * 32 + quad * 8);
            float4 ka = kp[0], kb = kp[1];
            short8 bb;
            bb[0] = (short)f2bfbits(ka.x); bb[1] = (short)f2bfbits(ka.y);
            bb[2] = (short)f2bfbits(ka.z); bb[3] = (short)f2bfbits(ka.w);
            bb[4] = (short)f2bfbits(kb.x); bb[5] = (short)f2bfbits(kb.y);
            bb[6] = (short)f2bfbits(kb.z); bb[7] = (short)f2bfbits(kb.w);
            bfr[hh][nt] = bb;
        }
    }

    f32x4 ac[4][2][2];
    #pragma unroll
    for (int m = 0; m < 4; m++)
        #pragma unroll
        for (int hh = 0; hh < 2; hh++)
            #pragma unroll
            for (int nt = 0; nt < 2; nt++)
                ac[m][hh][nt] = __builtin_amdgcn_mfma_f32_16x16x32_bf16(
                    afr[m][hh], bfr[hh][nt], (f32x4){0.f, 0.f, 0.f, 0.f}, 0, 0, 0);

    #pragma unroll
    for (int m = 0; m < 4; m++) {
        #pragma unroll
        for (int hh = 0; hh < 2; hh++) {
            #pragma unroll
            for (int nt = 0; nt < 2; nt++) {
                int col = (h0 + hh) * 32 + nt * 16 + lane15;
                int rowb = m * 16 + quad * 4;
                size_t img = ((size_t)((b * 8 + (col & 7)) * 32 + (col >> 3))) * 4096 + n0 + rowb;
                uint2 vv = *(const uint2*)(vloc + img);
                float vl[4] = {bf_lo(vv.x), bf_hi(vv.x), bf_lo(vv.y), bf_hi(vv.y)};
                #pragma unroll
                for (int i = 0; i < 4; i++) {
                    float gg = b2f(g16[(size_t)(r0 + rowb + i) * 256 + col]);
                    float val = (ac[m][hh][nt][i] + vl[i]) * gg;
                    QA[(rowb + i) * A2P + col] = f2bfbits(val);
                }
            }
        }
    }

    int wm = (w & 1) * 32, wn = (w >> 1) * 128;
    f32x4 acc2[2][8];
    #pragma unroll
    for (int mi = 0; mi < 2; mi++)
        #pragma unroll
        for (int ni = 0; ni < 8; ni++) acc2[mi][ni] = (f32x4){0.f, 0.f, 0.f, 0.f};

    for (int k0 = 0; k0 < 256; k0 += 32) {
        __syncthreads();
        #pragma unroll
        for (int i = 0; i < 4; i++) {
            int ncol = i * 64 + w * 16 + (l >> 2);
            gl_lds16(&Wt2[(size_t)ncol * 256 + k0 + (l & 3) * 8],
                     &Bs[(i * 64 + w * 16) * 32]);
        }
        __syncthreads();
        short8 a[2], bb[8];
        #pragma unroll
        for (int mi = 0; mi < 2; mi++)
            a[mi] = *(const short8*)&QA[(wm + mi * 16 + lane15) * A2P + k0 + quad * 8];
        #pragma unroll
        for (int ni = 0; ni < 8; ni++)
            bb[ni] = *(const short8*)&Bs[(wn + ni * 16 + lane15) * 32 + quad * 8];
        #pragma unroll
        for (int mi = 0; mi < 2; mi++)
            #pragma unroll
            for (int ni = 0; ni < 8; ni++)
                acc2[mi][ni] = __builtin_amdgcn_mfma_f32_16x16x32_bf16(a[mi], bb[ni], acc2[mi][ni], 0, 0, 0);
    }

    #pragma unroll
    for (int mi = 0; mi < 2; mi++) {
        #pragma unroll
        for (int ni = 0; ni < 8; ni++) {
            int row = r0 + wm + mi * 16 + quad * 4;
            int col = wn + ni * 16 + lane15;
            float bv = bp[col];
            #pragma unroll
            for (int r = 0; r < 4; r++)
                out[(size_t)(row + r) * 256 + col] = acc2[mi][ni][r] + bv;
        }
    }
}

extern "C" void kernel_launch(void* const* d_in, const int* in_sizes, int n_in,
                              void* d_out, int out_size, void* d_ws, size_t ws_size,
                              hipStream_t stream) {
    const float* x      = (const float*)d_in[0];
    const float* W_qg   = (const float*)d_in[1];
    const float* W_kv   = (const float*)d_in[2];
    const float* W_proj = (const float*)d_in[3];
    const float* b_proj = (const float*)d_in[4];
    const float* dwc_w  = (const float*)d_in[5];
    const float* dwc_b  = (const float*)d_in[6];
    const float* pow_p  = (const float*)d_in[7];
    float* out = (float*)d_out;

    float* ws = (float*)d_ws;
    const size_t E = E_;
    __hip_bfloat16* q16  = (__hip_bfloat16*)ws;                  // E bf16
    __hip_bfloat16* k16  = (__hip_bfloat16*)(ws + E / 2);        // E bf16
    __hip_bfloat16* g16  = (__hip_bfloat16*)(ws + E);            // E bf16
    __hip_bfloat16* v16  = (__hip_bfloat16*)(ws + 3 * E / 2);    // E bf16
    __hip_bfloat16* xb   = (__hip_bfloat16*)(ws + 2 * E);        // E bf16
    __hip_bfloat16* vl16 = (__hip_bfloat16*)(ws + 5 * E / 2);    // E bf16 (own buffer!)
    float* kv_mat2 = ws + 3 * E;                                 // 65536 floats
    __hip_bfloat16* Wt1 = (__hip_bfloat16*)(kv_mat2 + 65536);    // 262144 bf16
    __hip_bfloat16* Wt2 = Wt1 + 262144;                          // 65536 bf16
    float* powers = (float*)(Wt2 + 65536);                       // 256 floats

    hipMemsetAsync(kv_mat2, 0, 65536 * sizeof(float), stream);
    cvt_all<<<8192 + 81, 256, 0, stream>>>(x, W_qg, W_kv, W_proj, pow_p, xb, Wt1, Wt2, powers);
    gemm1_mfma<<<dim3(BN_ / 128, 8), 256, 0, stream>>>(xb, Wt1, powers, q16, k16, g16, v16);
    kvmat_conv<<<256 + 2048, 256, 0, stream>>>(k16, v16, kv_mat2, dwc_w, dwc_b, vl16);
    att_gemm2<<<512, 256, 0, stream>>>(q16, kv_mat2, vl16, g16, Wt2, b_proj, out);
}

// Round 8
// 217.214 us; speedup vs baseline: 1.0350x; 1.0350x over previous
//
#include <hip/hip_runtime.h>
#include <hip/hip_bf16.h>
#include <math.h>

#define B_ 8
#define N_ 4096
#define C_ 256
#define H_ 8
#define HD_ 32
#define BN_ (B_ * N_)  // 32768
#define E_ ((size_t)BN_ * C_)  // 8388608

typedef __attribute__((ext_vector_type(8))) short short8;
typedef __attribute__((ext_vector_type(4))) float f32x4;

__device__ __forceinline__ float b2f(__hip_bfloat16 x) { return __bfloat162float(x); }

__device__ __forceinline__ void gl_lds16(const void* gp, void* lp) {
    __builtin_amdgcn_global_load_lds(
        (const __attribute__((address_space(1))) unsigned int*)gp,
        (__attribute__((address_space(3))) unsigned int*)lp,
        16, 0, 0);
}

__device__ __forceinline__ float fast_abspow(float v, float p) {
    float av = fabsf(v);
    return (av > 0.f) ? exp2f(p * __log2f(av)) : 0.f;
}

__device__ __forceinline__ float bf_lo(unsigned u) { return __uint_as_float(u << 16); }
__device__ __forceinline__ float bf_hi(unsigned u) { return __uint_as_float(u & 0xffff0000u); }
__device__ __forceinline__ unsigned short f2bfbits(float f) {
    __hip_bfloat16 h = __float2bfloat16(f);
    return *(unsigned short*)&h;
}
__device__ __forceinline__ unsigned pack2(float lo, float hi) {
    return (unsigned)f2bfbits(lo) | ((unsigned)f2bfbits(hi) << 16);
}

// ---- merged converts: blocks [0,4096): x -> bf16 (vectorized); [4096, 4177): weights+powers ----
__global__ __launch_bounds__(256) void cvt_all(
    const float* __restrict__ x, const float* __restrict__ Wqg,
    const float* __restrict__ Wkv, const float* __restrict__ Wp,
    const float* __restrict__ pp,
    __hip_bfloat16* __restrict__ xb, __hip_bfloat16* __restrict__ Wt1,
    __hip_bfloat16* __restrict__ Wt2, float* __restrict__ powers)
{
    int t = threadIdx.x;
    int bid0 = blockIdx.x;
    if (bid0 < 4096) {
        size_t i = ((size_t)bid0 * 256 + t) * 8;
        float4 a = *(const float4*)&x[i];
        float4 b = *(const float4*)&x[i + 4];
        uint4 o = {pack2(a.x, a.y), pack2(a.z, a.w), pack2(b.x, b.y), pack2(b.z, b.w)};
        *(uint4*)&xb[i] = o;
        return;
    }
    int bid = bid0 - 4096;
    if (bid == 80) {
        powers[t] = 1.0f + 4.0f / (1.0f + expf(-pp[t]));
        return;
    }
    __shared__ float tile[64][65];
    const float* src;
    __hip_bfloat16* dst;
    int scols, tr, tc, dn0;
    if (bid < 32)      { src = Wqg; scols = 512; tr = bid >> 3;        tc = bid & 7;        dst = Wt1; dn0 = tc * 64; }
    else if (bid < 64) { src = Wkv; scols = 512; tr = (bid - 32) >> 3; tc = (bid - 32) & 7; dst = Wt1; dn0 = 512 + tc * 64; }
    else               { src = Wp;  scols = 256; tr = (bid - 64) >> 2; tc = (bid - 64) & 3; dst = Wt2; dn0 = tc * 64; }
    int tx = t & 63, ty = t >> 6;
    #pragma unroll
    for (int i = 0; i < 16; i++) {
        int r = ty + i * 4;
        tile[r][tx] = src[(size_t)(tr * 64 + r) * scols + tc * 64 + tx];
    }
    __syncthreads();
    #pragma unroll
    for (int i = 0; i < 16; i++) {
        int n_local = ty + i * 4;
        dst[(size_t)(dn0 + n_local) * 256 + tr * 64 + tx] = __float2bfloat16(tile[tx][n_local]);
    }
}

// ---- GEMM1: 128x128 tile, BK=64; epilogue via LDS transpose + uint4 stores ----
#define EP 132  // epilogue LDS row stride (shorts)
__global__ __launch_bounds__(256) void gemm1_mfma(
    const __hip_bfloat16* __restrict__ xb, const __hip_bfloat16* __restrict__ Wt1,
    const float* __restrict__ powers,
    __hip_bfloat16* __restrict__ q16, __hip_bfloat16* __restrict__ k16,
    __hip_bfloat16* __restrict__ g16, __hip_bfloat16* __restrict__ v16)
{
    __shared__ __align__(16) unsigned short SMEM[128 * EP];
    unsigned short* As = SMEM;          // 8192 shorts
    unsigned short* Bs = SMEM + 8192;   // 8192 shorts
    int t = threadIdx.x;
    int w = t >> 6, l = t & 63;
    int row0 = blockIdx.x * 128;
    int col0 = blockIdx.y * 128;
    int wm = (w >> 1) * 64, wn = (w & 1) * 64;
    int lane15 = l & 15, quad = l >> 4;
    int srow = l >> 2;
    int skcol = (l & 3) * 8;

    f32x4 acc[4][4];
    #pragma unroll
    for (int mi = 0; mi < 4; mi++)
        #pragma unroll
        for (int ni = 0; ni < 4; ni++) acc[mi][ni] = (f32x4){0.f, 0.f, 0.f, 0.f};

    for (int k0 = 0; k0 < 256; k0 += 64) {
        #pragma unroll
        for (int kh = 0; kh < 2; kh++) {
            #pragma unroll
            for (int i = 0; i < 2; i++) {
                int r = i * 64 + w * 16 + srow;
                int kc = k0 + kh * 32 + skcol;
                gl_lds16(&xb[(size_t)(row0 + r) * 256 + kc],
                         &As[kh * 4096 + (i * 64 + w * 16) * 32]);
                gl_lds16(&Wt1[(size_t)(col0 + r) * 256 + kc],
                         &Bs[kh * 4096 + (i * 64 + w * 16) * 32]);
            }
        }
        __syncthreads();
        #pragma unroll
        for (int kh = 0; kh < 2; kh++) {
            short8 a[4], b[4];
            #pragma unroll
            for (int mi = 0; mi < 4; mi++)
                a[mi] = *(const short8*)&As[kh * 4096 + (wm + mi * 16 + lane15) * 32 + quad * 8];
            #pragma unroll
            for (int ni = 0; ni < 4; ni++)
                b[ni] = *(const short8*)&Bs[kh * 4096 + (wn + ni * 16 + lane15) * 32 + quad * 8];
            #pragma unroll
            for (int mi = 0; mi < 4; mi++)
                #pragma unroll
                for (int ni = 0; ni < 4; ni++)
                    acc[mi][ni] = __builtin_amdgcn_mfma_f32_16x16x32_bf16(a[mi], b[ni], acc[mi][ni], 0, 0, 0);
        }
        __syncthreads();
    }

    int region = blockIdx.y >> 1;  // 0:q 1:g 2:k 3:v
    bool dopow = (region == 0) || (region == 2);
    #pragma unroll
    for (int mi = 0; mi < 4; mi++) {
        #pragma unroll
        for (int ni = 0; ni < 4; ni++) {
            int lrow = wm + mi * 16 + quad * 4;
            int lcol = wn + ni * 16 + lane15;
            float p = powers[(col0 + lcol) & 255];
            #pragma unroll
            for (int r = 0; r < 4; r++) {
                float v = acc[mi][ni][r];
                float o = dopow ? fast_abspow(v, p) : v;
                SMEM[(lrow + r) * EP + lcol] = f2bfbits(o);
            }
        }
    }
    __syncthreads();
    __hip_bfloat16* dst = (region == 0) ? q16 : (region == 1) ? g16 : (region == 2) ? k16 : v16;
    int sr = t >> 1, sc = (t & 1) * 64;
    const unsigned short* src = &SMEM[sr * EP + sc];
    __hip_bfloat16* gp = dst + (size_t)(row0 + sr) * 256 + ((col0 + sc) & 255);
    #pragma unroll
    for (int j = 0; j < 8; j++)
        *(uint4*)(gp + j * 8) = *(const uint4*)(src + j * 8);
}

// ---- kvmat: grid 256 = b*32+seg (128 n each), atomic accumulate into kv_mat2 ----
__global__ __launch_bounds__(256) void kvmat_kernel(
    const __hip_bfloat16* __restrict__ k16, const __hip_bfloat16* __restrict__ v16,
    float* __restrict__ kv_mat2)
{
    __shared__ __align__(16) unsigned short Kl[16 * 256];
    __shared__ __align__(16) unsigned short Vl[16 * 256];
    int t = threadIdx.x;
    int bid = blockIdx.x;
    int b = bid >> 5, seg = bid & 31;
    int h = t >> 5;
    float acc[32];
    #pragma unroll
    for (int e = 0; e < 32; e++) acc[e] = 0.f;
    const size_t base = (size_t)b * N_ * 256;
    int row = t >> 4, colb = (t & 15) * 16;
    for (int n0 = seg * 128; n0 < seg * 128 + 128; n0 += 16) {
        const uint4* ks = (const uint4*)(k16 + base + (size_t)(n0 + row) * 256 + colb);
        uint4 ka = ks[0], kb = ks[1];
        const uint4* vs = (const uint4*)(v16 + base + (size_t)(n0 + row) * 256 + colb);
        uint4 va = vs[0], vb = vs[1];
        __syncthreads();
        uint4* kd4 = (uint4*)&Kl[row * 256 + colb];
        kd4[0] = ka; kd4[1] = kb;
        uint4* vd4 = (uint4*)&Vl[row * 256 + colb];
        vd4[0] = va; vd4[1] = vb;
        __syncthreads();
        #pragma unroll
        for (int nn = 0; nn < 16; nn++) {
            float kd = bf_lo((unsigned)Kl[nn * 256 + t]);
            const uint4* vp = (const uint4*)&Vl[nn * 256 + h * 32];
            uint4 v0 = vp[0], v1 = vp[1], v2 = vp[2], v3 = vp[3];
            unsigned us[16] = {v0.x, v0.y, v0.z, v0.w, v1.x, v1.y, v1.z, v1.w,
                               v2.x, v2.y, v2.z, v2.w, v3.x, v3.y, v3.z, v3.w};
            #pragma unroll
            for (int j = 0; j < 16; j++) {
                acc[2 * j]     += kd * bf_lo(us[j]);
                acc[2 * j + 1] += kd * bf_hi(us[j]);
            }
        }
    }
    float* dst = kv_mat2 + (size_t)b * 8192;
    #pragma unroll
    for (int e = 0; e < 32; e++) atomicAdd(&dst[e * 256 + t], acc[e]);
}

// ---- depthwise 5x5 conv, vectorized (standalone, low VGPR) ----
__global__ __launch_bounds__(256) void conv_kernel(
    const __hip_bfloat16* __restrict__ v16,
    const float* __restrict__ w, const float* __restrict__ bias,
    __hip_bfloat16* __restrict__ vloc)
{
    __shared__ __align__(16) float img[64 * 72];
    __shared__ float wl[25];
    int t = threadIdx.x;
    int gid = blockIdx.x;
    int DD = gid & 31;
    if (t < 128) {
        int row = t >> 1, side = (t & 1) * 68;
        *(float4*)&img[row * 72 + side] = (float4){0.f, 0.f, 0.f, 0.f};
    }
    if (t < 25) wl[t] = w[DD * 25 + t];
    {
        int row = t >> 2, colb = (t & 3) * 16;
        const uint4* src = (const uint4*)(v16 + (size_t)gid * 4096 + row * 64 + colb);
        uint4 u0 = src[0], u1 = src[1];
        float4* d = (float4*)&img[row * 72 + 4 + colb];
        d[0] = (float4){bf_lo(u0.x), bf_hi(u0.x), bf_lo(u0.y), bf_hi(u0.y)};
        d[1] = (float4){bf_lo(u0.z), bf_hi(u0.z), bf_lo(u0.w), bf_hi(u0.w)};
        d[2] = (float4){bf_lo(u1.x), bf_hi(u1.x), bf_lo(u1.y), bf_hi(u1.y)};
        d[3] = (float4){bf_lo(u1.z), bf_hi(u1.z), bf_lo(u1.w), bf_hi(u1.w)};
    }
    __syncthreads();
    float bs = bias[DD];
    int x0 = (t & 15) * 4, yb = t >> 4;
    #pragma unroll
    for (int s = 0; s < 4; s++) {
        int y = yb + s * 16;
        float a0 = bs, a1 = bs, a2 = bs, a3 = bs;
        #pragma unroll
        for (int ky = 0; ky < 5; ky++) {
            int row = y + ky - 2;
            if (row < 0 || row >= 64) continue;
            const float* rp = &img[row * 72 + x0];
            float4 w0 = *(const float4*)rp;
            float4 w1 = *(const float4*)(rp + 4);
            float4 w2 = *(const float4*)(rp + 8);
            float win[12] = {w0.x, w0.y, w0.z, w0.w, w1.x, w1.y, w1.z, w1.w,
                             w2.x, w2.y, w2.z, w2.w};
            #pragma unroll
            for (int kx = 0; kx < 5; kx++) {
                float wt = wl[ky * 5 + kx];
                a0 += wt * win[2 + kx];
                a1 += wt * win[3 + kx];
                a2 += wt * win[4 + kx];
                a3 += wt * win[5 + kx];
            }
        }
        unsigned lo = pack2(a0, a1);
        unsigned hi = pack2(a2, a3);
        *(uint2*)(vloc + (size_t)gid * 4096 + y * 64 + x0) = (uint2){lo, hi};
    }
}

// ---- fused MFMA att + gate + GEMM2: grid 512, 64 rows per block ----
#define A2P 264
__global__ __launch_bounds__(256) void att_gemm2(
    const __hip_bfloat16* __restrict__ q16, const float* __restrict__ kv_mat2,
    const __hip_bfloat16* __restrict__ vloc, const __hip_bfloat16* __restrict__ g16,
    const __hip_bfloat16* __restrict__ Wt2, const float* __restrict__ bp,
    float* __restrict__ out)
{
    __shared__ __align__(16) unsigned short QA[64 * A2P];
    __shared__ __align__(16) unsigned short Bs[256 * 32];
    int t = threadIdx.x;
    int w = t >> 6, l = t & 63;
    int r0 = blockIdx.x * 64;
    int b = r0 >> 12, n0 = r0 & 4095;
    int lane15 = l & 15, quad = l >> 4;
    int h0 = w * 2;

    {
        const uint4* qsrc = (const uint4*)(q16 + (size_t)(r0 + (t >> 2)) * 256 + (t & 3) * 64);
        uint4* qdst = (uint4*)&QA[(t >> 2) * A2P + (t & 3) * 64];
        #pragma unroll
        for (int j = 0; j < 8; j++) qdst[j] = qsrc[j];
    }
    __syncthreads();

    short8 afr[4][2];
    #pragma unroll
    for (int m = 0; m < 4; m++)
        #pragma unroll
        for (int hh = 0; hh < 2; hh++)
            afr[m][hh] = *(const short8*)&QA[(m * 16 + lane15) * A2P + (h0 + hh) * 32 + quad * 8];

    short8 bfr[2][2];
    #pragma unroll
    for (int hh = 0; hh < 2; hh++) {
        #pragma unroll
        for (int nt = 0; nt < 2; nt++) {
            const float4* kp = (const float4*)(kv_mat2 + (size_t)b * 8192 +
                (size_t)(nt * 16 + lane15) * 256 + (h0 + hh) * 32 + quad * 8);
            float4 ka = kp[0], kb = kp[1];
            short8 bb;
            bb[0] = (short)f2bfbits(ka.x); bb[1] = (short)f2bfbits(ka.y);
            bb[2] = (short)f2bfbits(ka.z); bb[3] = (short)f2bfbits(ka.w);
            bb[4] = (short)f2bfbits(kb.x); bb[5] = (short)f2bfbits(kb.y);
            bb[6] = (short)f2bfbits(kb.z); bb[7] = (short)f2bfbits(kb.w);
            bfr[hh][nt] = bb;
        }
    }

    f32x4 ac[4][2][2];
    #pragma unroll
    for (int m = 0; m < 4; m++)
        #pragma unroll
        for (int hh = 0; hh < 2; hh++)
            #pragma unroll
            for (int nt = 0; nt < 2; nt++)
                ac[m][hh][nt] = __builtin_amdgcn_mfma_f32_16x16x32_bf16(
                    afr[m][hh], bfr[hh][nt], (f32x4){0.f, 0.f, 0.f, 0.f}, 0, 0, 0);

    #pragma unroll
    for (int m = 0; m < 4; m++) {
        #pragma unroll
        for (int hh = 0; hh < 2; hh++) {
            #pragma unroll
            for (int nt = 0; nt < 2; nt++) {
                int col = (h0 + hh) * 32 + nt * 16 + lane15;
                int rowb = m * 16 + quad * 4;
                size_t img = ((size_t)((b * 8 + (col & 7)) * 32 + (col >> 3))) * 4096 + n0 + rowb;
                uint2 vv = *(const uint2*)(vloc + img);
                float vl[4] = {bf_lo(vv.x), bf_hi(vv.x), bf_lo(vv.y), bf_hi(vv.y)};
                #pragma unroll
                for (int i = 0; i < 4; i++) {
                    float gg = b2f(g16[(size_t)(r0 + rowb + i) * 256 + col]);
                    float val = (ac[m][hh][nt][i] + vl[i]) * gg;
                    QA[(rowb + i) * A2P + col] = f2bfbits(val);
                }
            }
        }
    }

    int wm = (w & 1) * 32, wn = (w >> 1) * 128;
    f32x4 acc2[2][8];
    #pragma unroll
    for (int mi = 0; mi < 2; mi++)
        #pragma unroll
        for (int ni = 0; ni < 8; ni++) acc2[mi][ni] = (f32x4){0.f, 0.f, 0.f, 0.f};

    for (int k0 = 0; k0 < 256; k0 += 32) {
        __syncthreads();
        #pragma unroll
        for (int i = 0; i < 4; i++) {
            int ncol = i * 64 + w * 16 + (l >> 2);
            gl_lds16(&Wt2[(size_t)ncol * 256 + k0 + (l & 3) * 8],
                     &Bs[(i * 64 + w * 16) * 32]);
        }
        __syncthreads();
        short8 a[2], bb[8];
        #pragma unroll
        for (int mi = 0; mi < 2; mi++)
            a[mi] = *(const short8*)&QA[(wm + mi * 16 + lane15) * A2P + k0 + quad * 8];
        #pragma unroll
        for (int ni = 0; ni < 8; ni++)
            bb[ni] = *(const short8*)&Bs[(wn + ni * 16 + lane15) * 32 + quad * 8];
        #pragma unroll
        for (int mi = 0; mi < 2; mi++)
            #pragma unroll
            for (int ni = 0; ni < 8; ni++)
                acc2[mi][ni] = __builtin_amdgcn_mfma_f32_16x16x32_bf16(a[mi], bb[ni], acc2[mi][ni], 0, 0, 0);
    }

    #pragma unroll
    for (int mi = 0; mi < 2; mi++) {
        #pragma unroll
        for (int ni = 0; ni < 8; ni++) {
            int row = r0 + wm + mi * 16 + quad * 4;
            int col = wn + ni * 16 + lane15;
            float bv = bp[col];
            #pragma unroll
            for (int r = 0; r < 4; r++)
                out[(size_t)(row + r) * 256 + col] = acc2[mi][ni][r] + bv;
        }
    }
}

extern "C" void kernel_launch(void* const* d_in, const int* in_sizes, int n_in,
                              void* d_out, int out_size, void* d_ws, size_t ws_size,
                              hipStream_t stream) {
    const float* x      = (const float*)d_in[0];
    const float* W_qg   = (const float*)d_in[1];
    const float* W_kv   = (const float*)d_in[2];
    const float* W_proj = (const float*)d_in[3];
    const float* b_proj = (const float*)d_in[4];
    const float* dwc_w  = (const float*)d_in[5];
    const float* dwc_b  = (const float*)d_in[6];
    const float* pow_p  = (const float*)d_in[7];
    float* out = (float*)d_out;

    float* ws = (float*)d_ws;
    const size_t E = E_;
    __hip_bfloat16* q16  = (__hip_bfloat16*)ws;                  // E bf16
    __hip_bfloat16* k16  = (__hip_bfloat16*)(ws + E / 2);        // E bf16
    __hip_bfloat16* g16  = (__hip_bfloat16*)(ws + E);            // E bf16
    __hip_bfloat16* v16  = (__hip_bfloat16*)(ws + 3 * E / 2);    // E bf16
    __hip_bfloat16* xb   = (__hip_bfloat16*)(ws + 2 * E);        // E bf16
    __hip_bfloat16* vl16 = (__hip_bfloat16*)(ws + 5 * E / 2);    // E bf16
    float* kv_mat2 = ws + 3 * E;                                 // 65536 floats
    __hip_bfloat16* Wt1 = (__hip_bfloat16*)(kv_mat2 + 65536);    // 262144 bf16
    __hip_bfloat16* Wt2 = Wt1 + 262144;                          // 65536 bf16
    float* powers = (float*)(Wt2 + 65536);                       // 256 floats

    hipMemsetAsync(kv_mat2, 0, 65536 * sizeof(float), stream);
    cvt_all<<<4096 + 81, 256, 0, stream>>>(x, W_qg, W_kv, W_proj, pow_p, xb, Wt1, Wt2, powers);
    gemm1_mfma<<<dim3(BN_ / 128, 8), 256, 0, stream>>>(xb, Wt1, powers, q16, k16, g16, v16);
    kvmat_kernel<<<256, 256, 0, stream>>>(k16, v16, kv_mat2);
    conv_kernel<<<2048, 256, 0, stream>>>(v16, dwc_w, dwc_b, vl16);
    att_gemm2<<<512, 256, 0, stream>>>(q16, kv_mat2, vl16, g16, Wt2, b_proj, out);
}

// Round 9
// 198.597 us; speedup vs baseline: 1.1320x; 1.0937x over previous
//
#include <hip/hip_runtime.h>
#include <hip/hip_bf16.h>
#include <math.h>

#define B_ 8
#define N_ 4096
#define C_ 256
#define H_ 8
#define HD_ 32
#define BN_ (B_ * N_)  // 32768
#define E_ ((size_t)BN_ * C_)  // 8388608

typedef __attribute__((ext_vector_type(8))) short short8;
typedef __attribute__((ext_vector_type(4))) float f32x4;

__device__ __forceinline__ float b2f(__hip_bfloat16 x) { return __bfloat162float(x); }

__device__ __forceinline__ void gl_lds16(const void* gp, void* lp) {
    __builtin_amdgcn_global_load_lds(
        (const __attribute__((address_space(1))) unsigned int*)gp,
        (__attribute__((address_space(3))) unsigned int*)lp,
        16, 0, 0);
}

// raw v_log_f32 / v_exp_f32 (base-2), no ocml fixup
__device__ __forceinline__ float fast_abspow(float v, float p) {
    float av = fabsf(v);
    return (av > 0.f) ? __builtin_amdgcn_exp2f(p * __builtin_amdgcn_logf(av)) : 0.f;
}

__device__ __forceinline__ float bf_lo(unsigned u) { return __uint_as_float(u << 16); }
__device__ __forceinline__ float bf_hi(unsigned u) { return __uint_as_float(u & 0xffff0000u); }
__device__ __forceinline__ unsigned short f2bfbits(float f) {
    __hip_bfloat16 h = __float2bfloat16(f);
    return *(unsigned short*)&h;
}
__device__ __forceinline__ unsigned pack2(float lo, float hi) {
    return (unsigned)f2bfbits(lo) | ((unsigned)f2bfbits(hi) << 16);
}

// ---- merged converts: blocks [0,4096): x -> bf16 (vectorized); [4096, 4177): weights+powers ----
__global__ __launch_bounds__(256) void cvt_all(
    const float* __restrict__ x, const float* __restrict__ Wqg,
    const float* __restrict__ Wkv, const float* __restrict__ Wp,
    const float* __restrict__ pp,
    __hip_bfloat16* __restrict__ xb, __hip_bfloat16* __restrict__ Wt1,
    __hip_bfloat16* __restrict__ Wt2, float* __restrict__ powers)
{
    int t = threadIdx.x;
    int bid0 = blockIdx.x;
    if (bid0 < 4096) {
        size_t i = ((size_t)bid0 * 256 + t) * 8;
        float4 a = *(const float4*)&x[i];
        float4 b = *(const float4*)&x[i + 4];
        uint4 o = {pack2(a.x, a.y), pack2(a.z, a.w), pack2(b.x, b.y), pack2(b.z, b.w)};
        *(uint4*)&xb[i] = o;
        return;
    }
    int bid = bid0 - 4096;
    if (bid == 80) {
        powers[t] = 1.0f + 4.0f / (1.0f + expf(-pp[t]));
        return;
    }
    __shared__ float tile[64][65];
    const float* src;
    __hip_bfloat16* dst;
    int scols, tr, tc, dn0;
    if (bid < 32)      { src = Wqg; scols = 512; tr = bid >> 3;        tc = bid & 7;        dst = Wt1; dn0 = tc * 64; }
    else if (bid < 64) { src = Wkv; scols = 512; tr = (bid - 32) >> 3; tc = (bid - 32) & 7; dst = Wt1; dn0 = 512 + tc * 64; }
    else               { src = Wp;  scols = 256; tr = (bid - 64) >> 2; tc = (bid - 64) & 3; dst = Wt2; dn0 = tc * 64; }
    int tx = t & 63, ty = t >> 6;
    #pragma unroll
    for (int i = 0; i < 16; i++) {
        int r = ty + i * 4;
        tile[r][tx] = src[(size_t)(tr * 64 + r) * scols + tc * 64 + tx];
    }
    __syncthreads();
    #pragma unroll
    for (int i = 0; i < 16; i++) {
        int n_local = ty + i * 4;
        dst[(size_t)(dn0 + n_local) * 256 + tr * 64 + tx] = __float2bfloat16(tile[tx][n_local]);
    }
}

// ---- GEMM1: 128x128 tile, BK=64, scattered-store epilogue (R6-best) ----
__global__ __launch_bounds__(256) void gemm1_mfma(
    const __hip_bfloat16* __restrict__ xb, const __hip_bfloat16* __restrict__ Wt1,
    const float* __restrict__ powers,
    __hip_bfloat16* __restrict__ q16, __hip_bfloat16* __restrict__ k16,
    __hip_bfloat16* __restrict__ g16, __hip_bfloat16* __restrict__ v16)
{
    __shared__ __align__(16) unsigned short As[2 * 128 * 32];
    __shared__ __align__(16) unsigned short Bs[2 * 128 * 32];
    int t = threadIdx.x;
    int w = t >> 6, l = t & 63;
    int row0 = blockIdx.x * 128;
    int col0 = blockIdx.y * 128;
    int wm = (w >> 1) * 64, wn = (w & 1) * 64;
    int lane15 = l & 15, quad = l >> 4;
    int srow = l >> 2;
    int skcol = (l & 3) * 8;

    f32x4 acc[4][4];
    #pragma unroll
    for (int mi = 0; mi < 4; mi++)
        #pragma unroll
        for (int ni = 0; ni < 4; ni++) acc[mi][ni] = (f32x4){0.f, 0.f, 0.f, 0.f};

    for (int k0 = 0; k0 < 256; k0 += 64) {
        #pragma unroll
        for (int kh = 0; kh < 2; kh++) {
            #pragma unroll
            for (int i = 0; i < 2; i++) {
                int r = i * 64 + w * 16 + srow;
                int kc = k0 + kh * 32 + skcol;
                gl_lds16(&xb[(size_t)(row0 + r) * 256 + kc],
                         &As[kh * 4096 + (i * 64 + w * 16) * 32]);
                gl_lds16(&Wt1[(size_t)(col0 + r) * 256 + kc],
                         &Bs[kh * 4096 + (i * 64 + w * 16) * 32]);
            }
        }
        __syncthreads();
        #pragma unroll
        for (int kh = 0; kh < 2; kh++) {
            short8 a[4], b[4];
            #pragma unroll
            for (int mi = 0; mi < 4; mi++)
                a[mi] = *(const short8*)&As[kh * 4096 + (wm + mi * 16 + lane15) * 32 + quad * 8];
            #pragma unroll
            for (int ni = 0; ni < 4; ni++)
                b[ni] = *(const short8*)&Bs[kh * 4096 + (wn + ni * 16 + lane15) * 32 + quad * 8];
            #pragma unroll
            for (int mi = 0; mi < 4; mi++)
                #pragma unroll
                for (int ni = 0; ni < 4; ni++)
                    acc[mi][ni] = __builtin_amdgcn_mfma_f32_16x16x32_bf16(a[mi], b[ni], acc[mi][ni], 0, 0, 0);
        }
        __syncthreads();
    }

    int region = blockIdx.y >> 1;  // 0:q 1:g 2:k 3:v
    bool dopow = (region == 0) || (region == 2);
    __hip_bfloat16* dst = (region == 0) ? q16 : (region == 1) ? g16 : (region == 2) ? k16 : v16;
    #pragma unroll
    for (int mi = 0; mi < 4; mi++) {
        #pragma unroll
        for (int ni = 0; ni < 4; ni++) {
            int row = row0 + wm + mi * 16 + quad * 4;
            int col = col0 + wn + ni * 16 + lane15;
            int c255 = col & 255;
            float p = powers[c255];
            #pragma unroll
            for (int r = 0; r < 4; r++) {
                float v = acc[mi][ni][r];
                float o = dopow ? fast_abspow(v, p) : v;
                dst[(size_t)(row + r) * 256 + c255] = __float2bfloat16(o);
            }
        }
    }
}

// ---- kvmat partials: grid 256 = b*32+seg (128 n each), LDS-staged panels ----
__global__ __launch_bounds__(256) void kvmat_kernel(
    const __hip_bfloat16* __restrict__ k16, const __hip_bfloat16* __restrict__ v16,
    float* __restrict__ kv_part)
{
    __shared__ __align__(16) unsigned short Kl[16 * 256];
    __shared__ __align__(16) unsigned short Vl[16 * 256];
    int t = threadIdx.x;
    int bid = blockIdx.x;
    int b = bid >> 5, seg = bid & 31;
    int h = t >> 5;
    float acc[32];
    #pragma unroll
    for (int e = 0; e < 32; e++) acc[e] = 0.f;
    const size_t base = (size_t)b * N_ * 256;
    int row = t >> 4, colb = (t & 15) * 16;
    for (int n0 = seg * 128; n0 < seg * 128 + 128; n0 += 16) {
        const uint4* ks = (const uint4*)(k16 + base + (size_t)(n0 + row) * 256 + colb);
        uint4 ka = ks[0], kb = ks[1];
        const uint4* vs = (const uint4*)(v16 + base + (size_t)(n0 + row) * 256 + colb);
        uint4 va = vs[0], vb = vs[1];
        __syncthreads();
        uint4* kd4 = (uint4*)&Kl[row * 256 + colb];
        kd4[0] = ka; kd4[1] = kb;
        uint4* vd4 = (uint4*)&Vl[row * 256 + colb];
        vd4[0] = va; vd4[1] = vb;
        __syncthreads();
        #pragma unroll
        for (int nn = 0; nn < 16; nn++) {
            float kd = bf_lo((unsigned)Kl[nn * 256 + t]);
            const uint4* vp = (const uint4*)&Vl[nn * 256 + h * 32];
            uint4 v0 = vp[0], v1 = vp[1], v2 = vp[2], v3 = vp[3];
            unsigned us[16] = {v0.x, v0.y, v0.z, v0.w, v1.x, v1.y, v1.z, v1.w,
                               v2.x, v2.y, v2.z, v2.w, v3.x, v3.y, v3.z, v3.w};
            #pragma unroll
            for (int j = 0; j < 16; j++) {
                acc[2 * j]     += kd * bf_lo(us[j]);
                acc[2 * j + 1] += kd * bf_hi(us[j]);
            }
        }
    }
    float* dst = kv_part + (size_t)bid * 8192;
    #pragma unroll
    for (int e = 0; e < 32; e++) dst[e * 256 + t] = acc[e];
}

// ---- reduce 32 segs -> kv_mat2[b][e*256 + h*32 + d] ; grid 64 = b*8+chunk ----
__global__ __launch_bounds__(256) void kv_reduce(
    const float* __restrict__ kv_part, float* __restrict__ kv_mat2)
{
    int bid = blockIdx.x, t = threadIdx.x;
    int b = bid >> 3, chunk = bid & 7;
    #pragma unroll
    for (int j = 0; j < 4; j++) {
        int i = chunk * 1024 + j * 256 + t;
        float s = 0.f;
        for (int seg = 0; seg < 32; seg++)
            s += kv_part[((size_t)b * 32 + seg) * 8192 + i];
        kv_mat2[(size_t)b * 8192 + i] = s;
    }
}

// ---- depthwise 5x5 conv, vectorized (standalone, low VGPR) ----
__global__ __launch_bounds__(256) void conv_kernel(
    const __hip_bfloat16* __restrict__ v16,
    const float* __restrict__ w, const float* __restrict__ bias,
    __hip_bfloat16* __restrict__ vloc)
{
    __shared__ __align__(16) float img[64 * 72];
    __shared__ float wl[25];
    int t = threadIdx.x;
    int gid = blockIdx.x;
    int DD = gid & 31;
    if (t < 128) {
        int row = t >> 1, side = (t & 1) * 68;
        *(float4*)&img[row * 72 + side] = (float4){0.f, 0.f, 0.f, 0.f};
    }
    if (t < 25) wl[t] = w[DD * 25 + t];
    {
        int row = t >> 2, colb = (t & 3) * 16;
        const uint4* src = (const uint4*)(v16 + (size_t)gid * 4096 + row * 64 + colb);
        uint4 u0 = src[0], u1 = src[1];
        float4* d = (float4*)&img[row * 72 + 4 + colb];
        d[0] = (float4){bf_lo(u0.x), bf_hi(u0.x), bf_lo(u0.y), bf_hi(u0.y)};
        d[1] = (float4){bf_lo(u0.z), bf_hi(u0.z), bf_lo(u0.w), bf_hi(u0.w)};
        d[2] = (float4){bf_lo(u1.x), bf_hi(u1.x), bf_lo(u1.y), bf_hi(u1.y)};
        d[3] = (float4){bf_lo(u1.z), bf_hi(u1.z), bf_lo(u1.w), bf_hi(u1.w)};
    }
    __syncthreads();
    float bs = bias[DD];
    int x0 = (t & 15) * 4, yb = t >> 4;
    #pragma unroll
    for (int s = 0; s < 4; s++) {
        int y = yb + s * 16;
        float a0 = bs, a1 = bs, a2 = bs, a3 = bs;
        #pragma unroll
        for (int ky = 0; ky < 5; ky++) {
            int row = y + ky - 2;
            if (row < 0 || row >= 64) continue;
            const float* rp = &img[row * 72 + x0];
            float4 w0 = *(const float4*)rp;
            float4 w1 = *(const float4*)(rp + 4);
            float4 w2 = *(const float4*)(rp + 8);
            float win[12] = {w0.x, w0.y, w0.z, w0.w, w1.x, w1.y, w1.z, w1.w,
                             w2.x, w2.y, w2.z, w2.w};
            #pragma unroll
            for (int kx = 0; kx < 5; kx++) {
                float wt = wl[ky * 5 + kx];
                a0 += wt * win[2 + kx];
                a1 += wt * win[3 + kx];
                a2 += wt * win[4 + kx];
                a3 += wt * win[5 + kx];
            }
        }
        unsigned lo = pack2(a0, a1);
        unsigned hi = pack2(a2, a3);
        *(uint2*)(vloc + (size_t)gid * 4096 + y * 64 + x0) = (uint2){lo, hi};
    }
}

// ---- fused MFMA att + gate + GEMM2: grid 512, 64 rows per block ----
#define A2P 264
__global__ __launch_bounds__(256) void att_gemm2(
    const __hip_bfloat16* __restrict__ q16, const float* __restrict__ kv_mat2,
    const __hip_bfloat16* __restrict__ vloc, const __hip_bfloat16* __restrict__ g16,
    const __hip_bfloat16* __restrict__ Wt2, const float* __restrict__ bp,
    float* __restrict__ out)
{
    __shared__ __align__(16) unsigned short QA[64 * A2P];
    __shared__ __align__(16) unsigned short Bs[256 * 32];
    int t = threadIdx.x;
    int w = t >> 6, l = t & 63;
    int r0 = blockIdx.x * 64;
    int b = r0 >> 12, n0 = r0 & 4095;
    int lane15 = l & 15, quad = l >> 4;
    int h0 = w * 2;

    {
        const uint4* qsrc = (const uint4*)(q16 + (size_t)(r0 + (t >> 2)) * 256 + (t & 3) * 64);
        uint4* qdst = (uint4*)&QA[(t >> 2) * A2P + (t & 3) * 64];
        #pragma unroll
        for (int j = 0; j < 8; j++) qdst[j] = qsrc[j];
    }
    __syncthreads();

    short8 afr[4][2];
    #pragma unroll
    for (int m = 0; m < 4; m++)
        #pragma unroll
        for (int hh = 0; hh < 2; hh++)
            afr[m][hh] = *(const short8*)&QA[(m * 16 + lane15) * A2P + (h0 + hh) * 32 + quad * 8];

    short8 bfr[2][2];
    #pragma unroll
    for (int hh = 0; hh < 2; hh++) {
        #pragma unroll
        for (int nt = 0; nt < 2; nt++) {
            const float4* kp = (const float4*)(kv_mat2 + (size_t)b * 8192 +
                (size_t)(nt * 16 + lane15) * 256 + (h0 + hh) * 32 + quad * 8);
            float4 ka = kp[0], kb = kp[1];
            short8 bb;
            bb[0] = (short)f2bfbits(ka.x); bb[1] = (short)f2bfbits(ka.y);
            bb[2] = (short)f2bfbits(ka.z); bb[3] = (short)f2bfbits(ka.w);
            bb[4] = (short)f2bfbits(kb.x); bb[5] = (short)f2bfbits(kb.y);
            bb[6] = (short)f2bfbits(kb.z); bb[7] = (short)f2bfbits(kb.w);
            bfr[hh][nt] = bb;
        }
    }

    f32x4 ac[4][2][2];
    #pragma unroll
    for (int m = 0; m < 4; m++)
        #pragma unroll
        for (int hh = 0; hh < 2; hh++)
            #pragma unroll
            for (int nt = 0; nt < 2; nt++)
                ac[m][hh][nt] = __builtin_amdgcn_mfma_f32_16x16x32_bf16(
                    afr[m][hh], bfr[hh][nt], (f32x4){0.f, 0.f, 0.f, 0.f}, 0, 0, 0);

    #pragma unroll
    for (int m = 0; m < 4; m++) {
        #pragma unroll
        for (int hh = 0; hh < 2; hh++) {
            #pragma unroll
            for (int nt = 0; nt < 2; nt++) {
                int col = (h0 + hh) * 32 + nt * 16 + lane15;
                int rowb = m * 16 + quad * 4;
                size_t img = ((size_t)((b * 8 + (col & 7)) * 32 + (col >> 3))) * 4096 + n0 + rowb;
                uint2 vv = *(const uint2*)(vloc + img);
                float vl[4] = {bf_lo(vv.x), bf_hi(vv.x), bf_lo(vv.y), bf_hi(vv.y)};
                #pragma unroll
                for (int i = 0; i < 4; i++) {
                    float gg = b2f(g16[(size_t)(r0 + rowb + i) * 256 + col]);
                    float val = (ac[m][hh][nt][i] + vl[i]) * gg;
                    QA[(rowb + i) * A2P + col] = f2bfbits(val);
                }
            }
        }
    }

    int wm = (w & 1) * 32, wn = (w >> 1) * 128;
    f32x4 acc2[2][8];
    #pragma unroll
    for (int mi = 0; mi < 2; mi++)
        #pragma unroll
        for (int ni = 0; ni < 8; ni++) acc2[mi][ni] = (f32x4){0.f, 0.f, 0.f, 0.f};

    for (int k0 = 0; k0 < 256; k0 += 32) {
        __syncthreads();
        #pragma unroll
        for (int i = 0; i < 4; i++) {
            int ncol = i * 64 + w * 16 + (l >> 2);
            gl_lds16(&Wt2[(size_t)ncol * 256 + k0 + (l & 3) * 8],
                     &Bs[(i * 64 + w * 16) * 32]);
        }
        __syncthreads();
        short8 a[2], bb[8];
        #pragma unroll
        for (int mi = 0; mi < 2; mi++)
            a[mi] = *(const short8*)&QA[(wm + mi * 16 + lane15) * A2P + k0 + quad * 8];
        #pragma unroll
        for (int ni = 0; ni < 8; ni++)
            bb[ni] = *(const short8*)&Bs[(wn + ni * 16 + lane15) * 32 + quad * 8];
        #pragma unroll
        for (int mi = 0; mi < 2; mi++)
            #pragma unroll
            for (int ni = 0; ni < 8; ni++)
                acc2[mi][ni] = __builtin_amdgcn_mfma_f32_16x16x32_bf16(a[mi], bb[ni], acc2[mi][ni], 0, 0, 0);
    }

    #pragma unroll
    for (int mi = 0; mi < 2; mi++) {
        #pragma unroll
        for (int ni = 0; ni < 8; ni++) {
            int row = r0 + wm + mi * 16 + quad * 4;
            int col = wn + ni * 16 + lane15;
            float bv = bp[col];
            #pragma unroll
            for (int r = 0; r < 4; r++)
                out[(size_t)(row + r) * 256 + col] = acc2[mi][ni][r] + bv;
        }
    }
}

extern "C" void kernel_launch(void* const* d_in, const int* in_sizes, int n_in,
                              void* d_out, int out_size, void* d_ws, size_t ws_size,
                              hipStream_t stream) {
    const float* x      = (const float*)d_in[0];
    const float* W_qg   = (const float*)d_in[1];
    const float* W_kv   = (const float*)d_in[2];
    const float* W_proj = (const float*)d_in[3];
    const float* b_proj = (const float*)d_in[4];
    const float* dwc_w  = (const float*)d_in[5];
    const float* dwc_b  = (const float*)d_in[6];
    const float* pow_p  = (const float*)d_in[7];
    float* out = (float*)d_out;

    float* ws = (float*)d_ws;
    const size_t E = E_;
    __hip_bfloat16* q16  = (__hip_bfloat16*)ws;                  // E bf16
    __hip_bfloat16* k16  = (__hip_bfloat16*)(ws + E / 2);        // E bf16
    __hip_bfloat16* g16  = (__hip_bfloat16*)(ws + E);            // E bf16
    __hip_bfloat16* v16  = (__hip_bfloat16*)(ws + 3 * E / 2);    // E bf16
    __hip_bfloat16* xb   = (__hip_bfloat16*)(ws + 2 * E);        // E bf16
    __hip_bfloat16* vl16 = (__hip_bfloat16*)(ws + 5 * E / 2);    // E bf16
    float* kv_part = ws + 3 * E;                                 // 256*8192 floats (8 MB)
    float* kv_mat2 = kv_part + 256 * 8192;                       // 65536 floats
    __hip_bfloat16* Wt1 = (__hip_bfloat16*)(kv_mat2 + 65536);    // 262144 bf16
    __hip_bfloat16* Wt2 = Wt1 + 262144;                          // 65536 bf16
    float* powers = (float*)(Wt2 + 65536);                       // 256 floats

    cvt_all<<<4096 + 81, 256, 0, stream>>>(x, W_qg, W_kv, W_proj, pow_p, xb, Wt1, Wt2, powers);
    gemm1_mfma<<<dim3(BN_ / 128, 8), 256, 0, stream>>>(xb, Wt1, powers, q16, k16, g16, v16);
    kvmat_kernel<<<256, 256, 0, stream>>>(k16, v16, kv_part);
    kv_reduce<<<64, 256, 0, stream>>>(kv_part, kv_mat2);
    conv_kernel<<<2048, 256, 0, stream>>>(v16, dwc_w, dwc_b, vl16);
    att_gemm2<<<512, 256, 0, stream>>>(q16, kv_mat2, vl16, g16, Wt2, b_proj, out);
}